// Round 14
// baseline (113.547 us; speedup 1.0000x reference)
//
#include <hip/hip_runtime.h>
#include <hip/hip_bf16.h>

typedef unsigned short u16;
typedef unsigned int u32;
typedef __attribute__((ext_vector_type(8))) short bf16x8;
typedef __attribute__((ext_vector_type(4))) float f32x4;
typedef __attribute__((ext_vector_type(2))) float f32x2;
typedef __attribute__((ext_vector_type(4))) unsigned short u16x4;

#define NBLK 256   // 256 blocks x 512 rows = 131072 rows; 1 block/CU (LDS-capped)

// shared_exp = floor(log2(amax)) - 8 ; scale = 2^shared_exp (power of two)
__device__ __forceinline__ void block_scale(float amax, float& scale, float& inv_scale) {
    int be = (int)(__float_as_uint(amax) >> 23);   // biased exponent, amax >= 0
    be = be < 8 ? 8 : be;                          // tiny/zero blocks quantize to 0 anyway
    scale     = __uint_as_float((unsigned)(be - 8) << 23);   // 2^(be-135)
    inv_scale = __uint_as_float((unsigned)(262 - be) << 23); // 2^(135-be)
}

#if __has_builtin(__builtin_amdgcn_cvt_pk_fp8_f32) && __has_builtin(__builtin_amdgcn_cvt_pk_f32_fp8)
#define HAS_HW_FP8 1
#else
#define HAS_HW_FP8 0
#endif

#if !HAS_HW_FP8
// Fallback: exact bit-math e4m3 RNE (verified in round 0)
__device__ __forceinline__ float mx_e4m3(float x, float inv_scale, float scale) {
    float v  = x * inv_scale;
    float av = fabsf(v);
    int e = (int)(__float_as_uint(av) >> 23) - 127;
    e = e < -6 ? -6 : (e > 8 ? 8 : e);
    float qs = __uint_as_float((unsigned)(130 - e) << 23);
    float qm = __uint_as_float((unsigned)(124 + e) << 23);
    float q  = fminf(rintf(av * qs) * qm, 448.0f);
    return copysignf(q, v) * scale;
}
#endif

// Quantize 4 elems to e4m3 grid (RNE, saturate 448), return bf16 bits of value*scale.
__device__ __forceinline__ u16x4 quant4(float4 v, float inv, float sc) {
    u16x4 r;
#if HAS_HW_FP8
    float a = fminf(fmaxf(v.x * inv, -448.f), 448.f);
    float b = fminf(fmaxf(v.y * inv, -448.f), 448.f);
    float c = fminf(fmaxf(v.z * inv, -448.f), 448.f);
    float d = fminf(fmaxf(v.w * inv, -448.f), 448.f);
    int p = __builtin_amdgcn_cvt_pk_fp8_f32(a, b, 0, false);   // RNE f32->e4m3 (OCP)
    p     = __builtin_amdgcn_cvt_pk_fp8_f32(c, d, p, true);
    f32x2 lo = __builtin_amdgcn_cvt_pk_f32_fp8(p, false);      // exact e4m3->f32
    f32x2 hi = __builtin_amdgcn_cvt_pk_f32_fp8(p, true);
    r.x = (u16)(__float_as_uint(lo[0] * sc) >> 16);
    r.y = (u16)(__float_as_uint(lo[1] * sc) >> 16);
    r.z = (u16)(__float_as_uint(hi[0] * sc) >> 16);
    r.w = (u16)(__float_as_uint(hi[1] * sc) >> 16);
#else
    r.x = (u16)(__float_as_uint(mx_e4m3(v.x, inv, sc)) >> 16);
    r.y = (u16)(__float_as_uint(mx_e4m3(v.y, inv, sc)) >> 16);
    r.z = (u16)(__float_as_uint(mx_e4m3(v.z, inv, sc)) >> 16);
    r.w = (u16)(__float_as_uint(mx_e4m3(v.w, inv, sc)) >> 16);
#endif
    return r;
}

// Quantize 256x256 weight to bf16 fake-quant, stored TRANSPOSED: Bq[n*256+k].
__global__ void wq_kernel(const float* __restrict__ W, u16* __restrict__ Bq) {
    const int t  = blockIdx.x * blockDim.x + threadIdx.x;
    const int f  = t * 4;
    const int k  = f >> 8;
    const int n0 = f & 255;
    const float4 v = *(const float4*)(W + f);
    float am = fmaxf(fmaxf(fabsf(v.x), fabsf(v.y)), fmaxf(fabsf(v.z), fabsf(v.w)));
    am = fmaxf(am, __shfl_xor(am, 1));   // 8 lanes x 4 elems = one 32-elem MX block
    am = fmaxf(am, __shfl_xor(am, 2));
    am = fmaxf(am, __shfl_xor(am, 4));
    float sc, inv; block_scale(am, sc, inv);
    u16x4 q = quant4(v, inv, sc);
    Bq[(size_t)(n0 + 0) * 256 + k] = q.x;
    Bq[(size_t)(n0 + 1) * 256 + k] = q.y;
    Bq[(size_t)(n0 + 2) * 256 + k] = q.z;
    Bq[(size_t)(n0 + 3) * 256 + k] = q.w;
}

// R13 + T14 prefetch overlap:
//  - 1 block (8 waves) per CU; whole B (128 KB bf16 [n][k], XOR-swizzled) + bias
//    in LDS (one-time prologue, one __syncthreads).
//  - per 128-row strip: quant(t) from registers -> af[8]; THEN issue strip t+1's
//    16 float4 loads (in flight under the whole MFMA phase -> HBM streams during
//    LDS/MFMA work); MFMA in FOUR col-quarters (acc[4] live, peak regs ~125);
//    pure pacing s_barrier (no waitcnt -> vmcnt stays in flight, write frontier
//    stays compact: R13's proven traffic fix).
__global__ void __launch_bounds__(512, 1)
mx_gemm(const float* __restrict__ X, const u16* __restrict__ Bq,
        const float* __restrict__ bias, float* __restrict__ out)
{
    __shared__ u16   Bs[256 * 256];   // 128 KB, rows XOR-swizzled by (n&7)<<4
    __shared__ float bs[256];         // bias
    const int tid = threadIdx.x;
    const int w   = tid >> 6;
    const int l   = tid & 63;
    const int lr  = l & 15;
    const int lg  = l >> 4;
    const size_t rowblk = (size_t)blockIdx.x * 512;

    // ---- strip-0 X loads FIRST (arrive during B staging) ----
    float4 xv[16];
    {
        const float* xp = X + (rowblk + w * 16 + lr) * 256 + lg * 8;
        #pragma unroll
        for (int kp = 0; kp < 8; ++kp) {
            xv[2 * kp]     = *(const float4*)(xp + kp * 32);
            xv[2 * kp + 1] = *(const float4*)(xp + kp * 32 + 4);
        }
    }
    __builtin_amdgcn_sched_barrier(0);

    // ---- one-time prologue: B -> LDS swizzled; bias -> LDS ----
    #pragma unroll
    for (int i = 0; i < 16; ++i) {
        const u32 g = (u32)(tid + i * 512) * 16;        // linear byte offset in Bq
        const u32 d = g ^ (((g >> 9) & 7) << 4);        // XOR bits 4..6 by n&7
        *(bf16x8*)((char*)Bs + d) = *(const bf16x8*)((const char*)Bq + g);
    }
    if (tid < 256) bs[tid] = bias[tid];
    __syncthreads();

    const u32   swz = (u32)(lr & 7) << 4;
    const char* BsB = (const char*)Bs;

    #pragma unroll 1
    for (int s = 0; s < 4; ++s) {
        // ---- quantize strip s in-register: xv dies into af[8] ----
        bf16x8 af[8];
        #pragma unroll
        for (int ks = 0; ks < 8; ++ks) {
            const float4 v0 = xv[2 * ks], v1 = xv[2 * ks + 1];
            float am = fmaxf(fmaxf(fabsf(v0.x), fabsf(v0.y)), fmaxf(fabsf(v0.z), fabsf(v0.w)));
            am = fmaxf(am, fmaxf(fmaxf(fabsf(v1.x), fabsf(v1.y)), fmaxf(fabsf(v1.z), fabsf(v1.w))));
            am = fmaxf(am, __shfl_xor(am, 16));   // other lg lanes, same row
            am = fmaxf(am, __shfl_xor(am, 32));   // = one 32-elem MX block per row
            float sc, inv; block_scale(am, sc, inv);
            const u16x4 q0 = quant4(v0, inv, sc);
            const u16x4 q1 = quant4(v1, inv, sc);
            bf16x8 a;
            a[0] = (short)q0.x; a[1] = (short)q0.y; a[2] = (short)q0.z; a[3] = (short)q0.w;
            a[4] = (short)q1.x; a[5] = (short)q1.y; a[6] = (short)q1.z; a[7] = (short)q1.w;
            af[ks] = a;
        }

        // ---- T14: issue strip t+1's loads NOW (stream under the MFMA phase) ----
        if (s < 3) {
            const float* xn = X + (rowblk + (size_t)(s + 1) * 128 + w * 16 + lr) * 256 + lg * 8;
            #pragma unroll
            for (int kp = 0; kp < 8; ++kp) {
                xv[2 * kp]     = *(const float4*)(xn + kp * 32);
                xv[2 * kp + 1] = *(const float4*)(xn + kp * 32 + 4);
            }
        }
        __builtin_amdgcn_sched_barrier(0);   // pin load issue above the MFMA phase

        // ---- MFMA in four col-quarters (acc[4] live) vs LDS-resident B ----
        float* op = out + (rowblk + (size_t)s * 128 + w * 16 + lr) * 256 + lg * 4;
        #pragma unroll
        for (int h = 0; h < 4; ++h) {
            f32x4 acc[4];
            #pragma unroll
            for (int ct = 0; ct < 4; ++ct)
                acc[ct] = *(const f32x4*)(bs + (h * 4 + ct) * 16 + lg * 4);
            #pragma unroll
            for (int ks = 0; ks < 8; ++ks) {
                #pragma unroll
                for (int ct = 0; ct < 4; ++ct) {
                    const u32 off = ((u32)(((h * 4 + ct) * 16 + lr) * 512 + ks * 64 + lg * 16)) ^ swz;
                    const bf16x8 bf = *(const bf16x8*)(BsB + off);
                    acc[ct] = __builtin_amdgcn_mfma_f32_16x16x32_bf16(bf, af[ks], acc[ct], 0, 0, 0);
                }
            }
            #pragma unroll
            for (int ct = 0; ct < 4; ++ct)
                *(f32x4*)(op + (h * 4 + ct) * 16) = acc[ct];
        }

        // ---- pure pacing barrier: no waitcnt, loads stay in flight ----
        if (s < 3) __builtin_amdgcn_s_barrier();
    }
}

extern "C" void kernel_launch(void* const* d_in, const int* in_sizes, int n_in,
                              void* d_out, int out_size, void* d_ws, size_t ws_size,
                              hipStream_t stream) {
    const float* x    = (const float*)d_in[0];
    const float* wk   = (const float*)d_in[1];
    const float* bias = (const float*)d_in[2];
    float* out = (float*)d_out;
    u16* Bq    = (u16*)d_ws;                  // 256*256 bf16 = 128 KB scratch
    wq_kernel<<<64, 256, 0, stream>>>(wk, Bq);
    mx_gemm<<<NBLK, 512, 0, stream>>>(x, Bq, bias, out);
}

// Round 15
// 99.780 us; speedup vs baseline: 1.1380x; 1.1380x over previous
//
#include <hip/hip_runtime.h>
#include <hip/hip_bf16.h>

typedef unsigned short u16;
typedef unsigned int u32;
typedef __attribute__((ext_vector_type(8))) short bf16x8;
typedef __attribute__((ext_vector_type(4))) float f32x4;
typedef __attribute__((ext_vector_type(2))) float f32x2;
typedef __attribute__((ext_vector_type(4))) unsigned short u16x4;

#define NBLK 256   // 256 blocks x 512 rows = 131072 rows; 1 block/CU (LDS-capped)

// shared_exp = floor(log2(amax)) - 8 ; scale = 2^shared_exp (power of two)
__device__ __forceinline__ void block_scale(float amax, float& scale, float& inv_scale) {
    int be = (int)(__float_as_uint(amax) >> 23);   // biased exponent, amax >= 0
    be = be < 8 ? 8 : be;                          // tiny/zero blocks quantize to 0 anyway
    scale     = __uint_as_float((unsigned)(be - 8) << 23);   // 2^(be-135)
    inv_scale = __uint_as_float((unsigned)(262 - be) << 23); // 2^(135-be)
}

#if __has_builtin(__builtin_amdgcn_cvt_pk_fp8_f32) && __has_builtin(__builtin_amdgcn_cvt_pk_f32_fp8)
#define HAS_HW_FP8 1
#else
#define HAS_HW_FP8 0
#endif

#if !HAS_HW_FP8
// Fallback: exact bit-math e4m3 RNE (verified in round 0)
__device__ __forceinline__ float mx_e4m3(float x, float inv_scale, float scale) {
    float v  = x * inv_scale;
    float av = fabsf(v);
    int e = (int)(__float_as_uint(av) >> 23) - 127;
    e = e < -6 ? -6 : (e > 8 ? 8 : e);
    float qs = __uint_as_float((unsigned)(130 - e) << 23);
    float qm = __uint_as_float((unsigned)(124 + e) << 23);
    float q  = fminf(rintf(av * qs) * qm, 448.0f);
    return copysignf(q, v) * scale;
}
#endif

// Quantize 4 elems to e4m3 grid (RNE, saturate 448), return bf16 bits of value*scale.
__device__ __forceinline__ u16x4 quant4(float4 v, float inv, float sc) {
    u16x4 r;
#if HAS_HW_FP8
    float a = fminf(fmaxf(v.x * inv, -448.f), 448.f);
    float b = fminf(fmaxf(v.y * inv, -448.f), 448.f);
    float c = fminf(fmaxf(v.z * inv, -448.f), 448.f);
    float d = fminf(fmaxf(v.w * inv, -448.f), 448.f);
    int p = __builtin_amdgcn_cvt_pk_fp8_f32(a, b, 0, false);   // RNE f32->e4m3 (OCP)
    p     = __builtin_amdgcn_cvt_pk_fp8_f32(c, d, p, true);
    f32x2 lo = __builtin_amdgcn_cvt_pk_f32_fp8(p, false);      // exact e4m3->f32
    f32x2 hi = __builtin_amdgcn_cvt_pk_f32_fp8(p, true);
    r.x = (u16)(__float_as_uint(lo[0] * sc) >> 16);
    r.y = (u16)(__float_as_uint(lo[1] * sc) >> 16);
    r.z = (u16)(__float_as_uint(hi[0] * sc) >> 16);
    r.w = (u16)(__float_as_uint(hi[1] * sc) >> 16);
#else
    r.x = (u16)(__float_as_uint(mx_e4m3(v.x, inv, sc)) >> 16);
    r.y = (u16)(__float_as_uint(mx_e4m3(v.y, inv, sc)) >> 16);
    r.z = (u16)(__float_as_uint(mx_e4m3(v.z, inv, sc)) >> 16);
    r.w = (u16)(__float_as_uint(mx_e4m3(v.w, inv, sc)) >> 16);
#endif
    return r;
}

// Quantize 256x256 weight to bf16 fake-quant, stored TRANSPOSED: Bq[n*256+k].
__global__ void wq_kernel(const float* __restrict__ W, u16* __restrict__ Bq) {
    const int t  = blockIdx.x * blockDim.x + threadIdx.x;
    const int f  = t * 4;
    const int k  = f >> 8;
    const int n0 = f & 255;
    const float4 v = *(const float4*)(W + f);
    float am = fmaxf(fmaxf(fabsf(v.x), fabsf(v.y)), fmaxf(fabsf(v.z), fabsf(v.w)));
    am = fmaxf(am, __shfl_xor(am, 1));   // 8 lanes x 4 elems = one 32-elem MX block
    am = fmaxf(am, __shfl_xor(am, 2));
    am = fmaxf(am, __shfl_xor(am, 4));
    float sc, inv; block_scale(am, sc, inv);
    u16x4 q = quant4(v, inv, sc);
    Bq[(size_t)(n0 + 0) * 256 + k] = q.x;
    Bq[(size_t)(n0 + 1) * 256 + k] = q.y;
    Bq[(size_t)(n0 + 2) * 256 + k] = q.z;
    Bq[(size_t)(n0 + 3) * 256 + k] = q.w;
}

// R13 + register-budgeted half-strip prefetch:
//  - 1 block (8 waves)/CU; whole B (128 KB bf16 [n][k], XOR-swizzled) + bias in
//    LDS (one-time prologue, one __syncthreads). Pacing s_barrier per strip
//    (no waitcnt -> loads/stores stay in flight; compact write frontier).
//  - per 128-row strip: quant (xa,xb die into af[8]) -> issue 8 loads of next
//    strip's FIRST half (xa, 32 VGPR live through MFMA; peak ~96 regs) ->
//    MFMA in four col-quarters (acc[4]) vs LDS B -> barrier -> issue next
//    strip's SECOND half (xb); its latency hides under quant ks0-3 (xa-resident).
__global__ void __launch_bounds__(512, 1)
mx_gemm(const float* __restrict__ X, const u16* __restrict__ Bq,
        const float* __restrict__ bias, float* __restrict__ out)
{
    __shared__ u16   Bs[256 * 256];   // 128 KB, rows XOR-swizzled by (n&7)<<4
    __shared__ float bs[256];         // bias
    const int tid = threadIdx.x;
    const int w   = tid >> 6;
    const int l   = tid & 63;
    const int lr  = l & 15;
    const int lg  = l >> 4;
    const size_t rowblk = (size_t)blockIdx.x * 512;

    // ---- one-time prologue: B -> LDS swizzled; bias -> LDS ----
    #pragma unroll
    for (int i = 0; i < 16; ++i) {
        const u32 g = (u32)(tid + i * 512) * 16;        // linear byte offset in Bq
        const u32 d = g ^ (((g >> 9) & 7) << 4);        // XOR bits 4..6 by n&7
        *(bf16x8*)((char*)Bs + d) = *(const bf16x8*)((const char*)Bq + g);
    }
    if (tid < 256) bs[tid] = bias[tid];
    __syncthreads();

    const u32   swz = (u32)(lr & 7) << 4;
    const char* BsB = (const char*)Bs;

    // ---- strip-0 loads (both halves) ----
    float4 xa[8], xb[8];
    {
        const float* xp = X + (rowblk + w * 16 + lr) * 256 + lg * 8;
        #pragma unroll
        for (int j = 0; j < 4; ++j) {
            xa[2 * j]     = *(const float4*)(xp + j * 32);
            xa[2 * j + 1] = *(const float4*)(xp + j * 32 + 4);
        }
        #pragma unroll
        for (int j = 0; j < 4; ++j) {
            xb[2 * j]     = *(const float4*)(xp + (j + 4) * 32);
            xb[2 * j + 1] = *(const float4*)(xp + (j + 4) * 32 + 4);
        }
    }

    #pragma unroll 1
    for (int s = 0; s < 4; ++s) {
        // ---- quantize strip s: xa (ks 0-3) + xb (ks 4-7) die into af[8] ----
        bf16x8 af[8];
        #pragma unroll
        for (int ks = 0; ks < 8; ++ks) {
            const float4 v0 = ks < 4 ? xa[2 * ks]     : xb[2 * (ks - 4)];
            const float4 v1 = ks < 4 ? xa[2 * ks + 1] : xb[2 * (ks - 4) + 1];
            float am = fmaxf(fmaxf(fabsf(v0.x), fabsf(v0.y)), fmaxf(fabsf(v0.z), fabsf(v0.w)));
            am = fmaxf(am, fmaxf(fmaxf(fabsf(v1.x), fabsf(v1.y)), fmaxf(fabsf(v1.z), fabsf(v1.w))));
            am = fmaxf(am, __shfl_xor(am, 16));   // other lg lanes, same row
            am = fmaxf(am, __shfl_xor(am, 32));   // = one 32-elem MX block per row
            float sc, inv; block_scale(am, sc, inv);
            const u16x4 q0 = quant4(v0, inv, sc);
            const u16x4 q1 = quant4(v1, inv, sc);
            bf16x8 a;
            a[0] = (short)q0.x; a[1] = (short)q0.y; a[2] = (short)q0.z; a[3] = (short)q0.w;
            a[4] = (short)q1.x; a[5] = (short)q1.y; a[6] = (short)q1.z; a[7] = (short)q1.w;
            af[ks] = a;
        }

        // ---- prefetch FIRST half of strip s+1 (8 loads, 32 VGPR live) ----
        if (s < 3) {
            const float* xn = X + (rowblk + (size_t)(s + 1) * 128 + w * 16 + lr) * 256 + lg * 8;
            #pragma unroll
            for (int j = 0; j < 4; ++j) {
                xa[2 * j]     = *(const float4*)(xn + j * 32);
                xa[2 * j + 1] = *(const float4*)(xn + j * 32 + 4);
            }
        }
        __builtin_amdgcn_sched_barrier(0);   // pin prefetch issue above MFMA phase

        // ---- MFMA in four col-quarters (acc[4] live) vs LDS-resident B ----
        float* op = out + (rowblk + (size_t)s * 128 + w * 16 + lr) * 256 + lg * 4;
        #pragma unroll
        for (int h = 0; h < 4; ++h) {
            f32x4 acc[4];
            #pragma unroll
            for (int ct = 0; ct < 4; ++ct)
                acc[ct] = *(const f32x4*)(bs + (h * 4 + ct) * 16 + lg * 4);
            #pragma unroll
            for (int ks = 0; ks < 8; ++ks) {
                #pragma unroll
                for (int ct = 0; ct < 4; ++ct) {
                    const u32 off = ((u32)(((h * 4 + ct) * 16 + lr) * 512 + ks * 64 + lg * 16)) ^ swz;
                    const bf16x8 bf = *(const bf16x8*)(BsB + off);
                    acc[ct] = __builtin_amdgcn_mfma_f32_16x16x32_bf16(bf, af[ks], acc[ct], 0, 0, 0);
                }
            }
            #pragma unroll
            for (int ct = 0; ct < 4; ++ct)
                *(f32x4*)(op + (h * 4 + ct) * 16) = acc[ct];
        }

        // ---- pacing barrier (no waitcnt), then SECOND-half prefetch of s+1 ----
        if (s < 3) {
            __builtin_amdgcn_s_barrier();
            const float* xn = X + (rowblk + (size_t)(s + 1) * 128 + w * 16 + lr) * 256 + lg * 8;
            #pragma unroll
            for (int j = 0; j < 4; ++j) {
                xb[2 * j]     = *(const float4*)(xn + (j + 4) * 32);
                xb[2 * j + 1] = *(const float4*)(xn + (j + 4) * 32 + 4);
            }
            __builtin_amdgcn_sched_barrier(0);   // issue before next quant begins
        }
    }
}

extern "C" void kernel_launch(void* const* d_in, const int* in_sizes, int n_in,
                              void* d_out, int out_size, void* d_ws, size_t ws_size,
                              hipStream_t stream) {
    const float* x    = (const float*)d_in[0];
    const float* wk   = (const float*)d_in[1];
    const float* bias = (const float*)d_in[2];
    float* out = (float*)d_out;
    u16* Bq    = (u16*)d_ws;                  // 256*256 bf16 = 128 KB scratch
    wq_kernel<<<64, 256, 0, stream>>>(wk, Bq);
    mx_gemm<<<NBLK, 512, 0, stream>>>(x, Bq, bias, out);
}